// Round 1
// baseline (422.926 us; speedup 1.0000x reference)
//
#include <hip/hip_runtime.h>

#define B_     16
#define N_IN_  6250
#define N_OUT_ 25000
#define C_     64
#define S_     9
#define NNZ_   75000

typedef __bf16 bf16x8 __attribute__((ext_vector_type(8)));
typedef float floatx4 __attribute__((ext_vector_type(4)));

// ---------------- CSR build ----------------

__global__ void hist_kernel(const int* __restrict__ rows, int* __restrict__ counts, int nnz) {
    int i = blockIdx.x * blockDim.x + threadIdx.x;
    if (i < nnz) atomicAdd(&counts[rows[i]], 1);
}

// Single-block exclusive scan of counts -> offsets; also re-initializes
// counts_cursor[i] = offsets[i] so fill_kernel can use it as a cursor.
__global__ void scan_kernel(int* __restrict__ counts_cursor, int* __restrict__ offsets, int n) {
    __shared__ int smem[1024];
    __shared__ int carry_s;
    int t = threadIdx.x;
    if (t == 0) carry_s = 0;
    __syncthreads();
    for (int base = 0; base < n; base += 1024) {
        int i = base + t;
        int v = (i < n) ? counts_cursor[i] : 0;
        smem[t] = v;
        __syncthreads();
        for (int off = 1; off < 1024; off <<= 1) {
            int x = (t >= off) ? smem[t - off] : 0;
            __syncthreads();
            smem[t] += x;
            __syncthreads();
        }
        int incl = smem[t];               // inclusive scan within chunk
        int base_carry = carry_s;         // stable: last write was 2 barriers ago
        if (i < n) {
            int excl = base_carry + incl - v;
            offsets[i] = excl;
            counts_cursor[i] = excl;      // becomes the fill cursor
        }
        __syncthreads();
        if (t == 1023) carry_s = base_carry + incl;
        __syncthreads();
    }
    if (t == 0) offsets[n] = carry_s;
}

__global__ void fill_kernel(const int* __restrict__ rows, const int* __restrict__ cols,
                            const float* __restrict__ vals, int* __restrict__ cursor,
                            int* __restrict__ ecol, float* __restrict__ eval, int nnz) {
    int i = blockIdx.x * blockDim.x + threadIdx.x;
    if (i < nnz) {
        int p = atomicAdd(&cursor[rows[i]], 1);
        ecol[p] = cols[i];
        eval[p] = vals[i];
    }
}

// ---------------- pooling (CSR gather) ----------------
// grid: (N_OUT/4, B), block 256. Wave = one (b,row); lanes = 64 channels.
__global__ void pool_kernel(const float* __restrict__ x, const int* __restrict__ offsets,
                            const int* __restrict__ ecol, const float* __restrict__ eval,
                            __bf16* __restrict__ pooled) {
    int b = blockIdx.y;
    int row = blockIdx.x * 4 + (threadIdx.x >> 6);
    int c = threadIdx.x & 63;
    int beg = offsets[row], end = offsets[row + 1];
    const float* xb = x + (size_t)b * N_IN_ * C_;
    float acc = 0.0f;
    for (int k = beg; k < end; ++k) {
        acc += xb[(size_t)ecol[k] * C_ + c] * eval[k];
    }
    pooled[((size_t)b * N_OUT_ + row) * C_ + c] = (__bf16)acc;
}

// ---------------- W -> Wt (bf16, transposed [64][576]) ----------------
__global__ void convw_kernel(const float* __restrict__ W, __bf16* __restrict__ Wt) {
    int i = blockIdx.x * blockDim.x + threadIdx.x;   // over 576*64
    if (i < 576 * 64) {
        int k = i >> 6, n = i & 63;
        Wt[n * 576 + k] = (__bf16)W[i];
    }
}

// ---------------- spiral gather + GEMM + bias + ELU ----------------
// grid: (ceil(N_OUT/64), B), block 256 (4 waves).
// Block computes out[b, otile*64 .. +63, 0..63].
__global__ __launch_bounds__(256) void gemm_kernel(
        const __bf16* __restrict__ pooled, const int* __restrict__ spiral,
        const __bf16* __restrict__ Wt, const float* __restrict__ bias,
        float* __restrict__ out) {
    __shared__ __bf16 At[64][72];   // [m][k], pad 72: 2-way bank alias only (free)
    __shared__ __bf16 Bt[64][72];   // [n][k] (B transposed so frag reads are contiguous)

    int b = blockIdx.y;
    int otile = blockIdx.x;
    int t = threadIdx.x;
    int wave = t >> 6, lane = t & 63;
    int quad = lane >> 4, l16 = lane & 15;

    const __bf16* poolb = pooled + (size_t)b * N_OUT_ * C_;

    floatx4 acc[4] = {};   // 4 N-tiles of 16, wave covers 16 M rows x 64 N cols

    for (int s = 0; s < S_; ++s) {
        // stage A: 64 rows x 64 ch, 16B per (thread,iter): 512 segs / 256 threads
        for (int i = t; i < 512; i += 256) {
            int r = i >> 3, seg = i & 7;
            int orow = otile * 64 + r;
            int4 val = {0, 0, 0, 0};
            if (orow < N_OUT_) {
                int src = spiral[orow * S_ + s];
                val = *reinterpret_cast<const int4*>(poolb + (size_t)src * C_ + seg * 8);
            }
            *reinterpret_cast<int4*>(&At[r][seg * 8]) = val;
        }
        // stage B: Bt[n][k] = Wt[n][s*64+k], 64 rows x 128B
        for (int i = t; i < 512; i += 256) {
            int n = i >> 3, seg = i & 7;
            *reinterpret_cast<int4*>(&Bt[n][seg * 8]) =
                *reinterpret_cast<const int4*>(Wt + n * 576 + s * 64 + seg * 8);
        }
        __syncthreads();

        #pragma unroll
        for (int kc = 0; kc < 2; ++kc) {
            bf16x8 a = *reinterpret_cast<const bf16x8*>(&At[wave * 16 + l16][kc * 32 + quad * 8]);
            #pragma unroll
            for (int nt = 0; nt < 4; ++nt) {
                bf16x8 bb = *reinterpret_cast<const bf16x8*>(&Bt[nt * 16 + l16][kc * 32 + quad * 8]);
                acc[nt] = __builtin_amdgcn_mfma_f32_16x16x32_bf16(a, bb, acc[nt], 0, 0, 0);
            }
        }
        __syncthreads();
    }

    // epilogue: lane holds D[m = quad*4 + reg][n = l16] per 16x16 tile
    #pragma unroll
    for (int nt = 0; nt < 4; ++nt) {
        #pragma unroll
        for (int i = 0; i < 4; ++i) {
            int m = otile * 64 + wave * 16 + quad * 4 + i;
            int n = nt * 16 + l16;
            if (m < N_OUT_) {
                float v = acc[nt][i] + bias[n];
                v = (v > 0.0f) ? v : expm1f(v);
                out[((size_t)b * N_OUT_ + m) * C_ + n] = v;
            }
        }
    }
}

extern "C" void kernel_launch(void* const* d_in, const int* in_sizes, int n_in,
                              void* d_out, int out_size, void* d_ws, size_t ws_size,
                              hipStream_t stream) {
    const float* x      = (const float*)d_in[0];
    const float* tvals  = (const float*)d_in[1];
    const int*   trow   = (const int*)d_in[2];
    const int*   tcol   = (const int*)d_in[3];
    const int*   spiral = (const int*)d_in[4];
    const float* W      = (const float*)d_in[5];
    const float* bias   = (const float*)d_in[6];
    float* out = (float*)d_out;

    char* ws = (char*)d_ws;
    size_t off = 0;
    auto alloc = [&](size_t bytes) -> void* {
        void* p = ws + off;
        off += (bytes + 255) & ~(size_t)255;
        return p;
    };
    __bf16* pooled  = (__bf16*)alloc((size_t)B_ * N_OUT_ * C_ * 2);   // 51.2 MB
    __bf16* Wt      = (__bf16*)alloc(576 * 64 * 2);
    int*    cursor  = (int*)alloc(N_OUT_ * 4);          // counts -> cursor
    int*    offsets = (int*)alloc((N_OUT_ + 1) * 4);
    int*    ecol    = (int*)alloc(NNZ_ * 4);
    float*  eval    = (float*)alloc(NNZ_ * 4);

    hipMemsetAsync(cursor, 0, N_OUT_ * 4, stream);
    hist_kernel<<<(NNZ_ + 255) / 256, 256, 0, stream>>>(trow, cursor, NNZ_);
    scan_kernel<<<1, 1024, 0, stream>>>(cursor, offsets, N_OUT_);
    fill_kernel<<<(NNZ_ + 255) / 256, 256, 0, stream>>>(trow, tcol, tvals, cursor, ecol, eval, NNZ_);
    pool_kernel<<<dim3(N_OUT_ / 4, B_), 256, 0, stream>>>(x, offsets, ecol, eval, pooled);
    convw_kernel<<<(576 * 64 + 255) / 256, 256, 0, stream>>>(W, Wt);
    gemm_kernel<<<dim3((N_OUT_ + 63) / 64, B_), 256, 0, stream>>>(pooled, spiral, Wt, bias, out);
}

// Round 2
// 358.092 us; speedup vs baseline: 1.1811x; 1.1811x over previous
//
#include <hip/hip_runtime.h>

#define B_     16
#define N_IN_  6250
#define N_OUT_ 25000
#define C_     64
#define S_     9
#define NNZ_   75000

typedef __bf16 bf16x8 __attribute__((ext_vector_type(8)));
typedef float floatx4 __attribute__((ext_vector_type(4)));

// ---------------- CSR build ----------------

__global__ void hist_kernel(const int* __restrict__ rows, int* __restrict__ counts, int nnz) {
    int i = blockIdx.x * blockDim.x + threadIdx.x;
    if (i < nnz) atomicAdd(&counts[rows[i]], 1);
}

// Single-block scan, shuffle-based (4 barriers/chunk instead of 20).
// counts_cursor[i] (counts in) -> offsets[i] (exclusive scan out) and
// counts_cursor[i] = offsets[i] (fill cursor).
__global__ void scan_kernel(int* __restrict__ counts_cursor, int* __restrict__ offsets, int n) {
    __shared__ int wsum[16];
    __shared__ int carry_s;
    int t = threadIdx.x;
    int wid = t >> 6, lane = t & 63;
    if (t == 0) carry_s = 0;
    __syncthreads();
    for (int base = 0; base < n; base += 1024) {
        int i = base + t;
        int v = (i < n) ? counts_cursor[i] : 0;
        // wave-inclusive scan via shfl
        int s = v;
        #pragma unroll
        for (int d = 1; d < 64; d <<= 1) {
            int u = __shfl_up(s, d, 64);
            if (lane >= d) s += u;
        }
        if (lane == 63) wsum[wid] = s;
        __syncthreads();
        if (wid == 0 && lane < 16) {
            int ws = wsum[lane];
            #pragma unroll
            for (int d = 1; d < 16; d <<= 1) {
                int u = __shfl_up(ws, d, 64);
                if (lane >= d) ws += u;
            }
            wsum[lane] = ws;   // inclusive over wave sums
        }
        __syncthreads();
        int wave_off = (wid == 0) ? 0 : wsum[wid - 1];
        int incl = s + wave_off + carry_s;   // inclusive global
        if (i < n) {
            int excl = incl - v;
            offsets[i] = excl;
            counts_cursor[i] = excl;
        }
        __syncthreads();                      // everyone has read carry_s
        if (t == 1023) carry_s = incl;        // chunk total + old carry
        __syncthreads();
    }
    if (t == 0) offsets[n] = carry_s;
}

__global__ void fill_kernel(const int* __restrict__ rows, const int* __restrict__ cols,
                            const float* __restrict__ vals, int* __restrict__ cursor,
                            int* __restrict__ ecol, float* __restrict__ eval, int nnz) {
    int i = blockIdx.x * blockDim.x + threadIdx.x;
    if (i < nnz) {
        int p = atomicAdd(&cursor[rows[i]], 1);
        ecol[p] = cols[i];
        eval[p] = vals[i];
    }
}

// ---------------- pooling (CSR gather), all batches per block ----------------
// grid: N_OUT blocks, block 256. Thread (bq, c): batches bq*4..bq*4+3, channel c.
// ecol/eval staged once per row; 4 independent gathers per nnz per thread (MLP=4).
__global__ __launch_bounds__(256) void pool_kernel(
        const float* __restrict__ x, const int* __restrict__ offsets,
        const int* __restrict__ ecol, const float* __restrict__ eval,
        __bf16* __restrict__ pooled) {
    __shared__ int   scol[64];
    __shared__ float sval[64];
    int row = blockIdx.x;
    int t = threadIdx.x;
    int c = t & 63, bq = t >> 6;
    int beg = offsets[row], end = offsets[row + 1];
    int count = end - beg;

    float acc[4] = {0.f, 0.f, 0.f, 0.f};
    for (int base = 0; base < count; base += 64) {
        int nb = min(64, count - base);
        if (t < nb) {
            scol[t] = ecol[beg + base + t];
            sval[t] = eval[beg + base + t];
        }
        __syncthreads();
        for (int k = 0; k < nb; ++k) {
            int col = scol[k];
            float v = sval[k];
            const float* xp = x + ((size_t)col * C_ + c);
            #pragma unroll
            for (int j = 0; j < 4; ++j) {
                acc[j] += xp[(size_t)(bq * 4 + j) * N_IN_ * C_] * v;
            }
        }
        __syncthreads();
    }
    #pragma unroll
    for (int j = 0; j < 4; ++j) {
        pooled[((size_t)(bq * 4 + j) * N_OUT_ + row) * C_ + c] = (__bf16)acc[j];
    }
}

// ---------------- W -> Wt (bf16, transposed [64][576]) ----------------
__global__ void convw_kernel(const float* __restrict__ W, __bf16* __restrict__ Wt) {
    int i = blockIdx.x * blockDim.x + threadIdx.x;   // over 576*64
    if (i < 576 * 64) {
        int k = i >> 6, n = i & 63;
        Wt[n * 576 + k] = (__bf16)W[i];
    }
}

// ---------------- spiral gather + GEMM + bias + ELU ----------------
// NO LDS, NO BARRIERS. grid: (ceil(N_OUT/256), B), block 256 (4 waves).
// Wave = 64 rows (4 m-tiles of 16) x 64 cols (4 n-tiles of 16).
// A-frags gathered straight from pooled (16B/lane contiguous, matches
// A[m=lane&15][k=quad*8+j]); B-frags from L2-hot Wt (73 KB).
__global__ __launch_bounds__(256, 2) void gemm_kernel(
        const __bf16* __restrict__ pooled, const int* __restrict__ spiral,
        const __bf16* __restrict__ Wt, const float* __restrict__ bias,
        float* __restrict__ out) {
    int b = blockIdx.y;
    int t = threadIdx.x;
    int wave = t >> 6, lane = t & 63;
    int quad = lane >> 4, l16 = lane & 15;
    int rowbase = blockIdx.x * 256 + wave * 64;

    const __bf16* poolb = pooled + (size_t)b * N_OUT_ * C_;

    floatx4 acc[4][4] = {};   // [mi][nt]

    for (int s = 0; s < S_; ++s) {
        int src[4];
        #pragma unroll
        for (int mi = 0; mi < 4; ++mi) {
            int m = rowbase + mi * 16 + l16;
            src[mi] = (m < N_OUT_) ? spiral[m * S_ + s] : 0;
        }
        #pragma unroll
        for (int kc = 0; kc < 2; ++kc) {
            bf16x8 a[4], bb[4];
            #pragma unroll
            for (int mi = 0; mi < 4; ++mi) {
                a[mi] = *reinterpret_cast<const bf16x8*>(
                    poolb + (size_t)src[mi] * C_ + kc * 32 + quad * 8);
            }
            #pragma unroll
            for (int nt = 0; nt < 4; ++nt) {
                bb[nt] = *reinterpret_cast<const bf16x8*>(
                    Wt + (nt * 16 + l16) * 576 + s * 64 + kc * 32 + quad * 8);
            }
            #pragma unroll
            for (int mi = 0; mi < 4; ++mi) {
                #pragma unroll
                for (int nt = 0; nt < 4; ++nt) {
                    acc[mi][nt] = __builtin_amdgcn_mfma_f32_16x16x32_bf16(
                        a[mi], bb[nt], acc[mi][nt], 0, 0, 0);
                }
            }
        }
    }

    // epilogue: tile D[m = quad*4 + reg][n = l16]
    #pragma unroll
    for (int nt = 0; nt < 4; ++nt) {
        float bn = bias[nt * 16 + l16];
        #pragma unroll
        for (int mi = 0; mi < 4; ++mi) {
            #pragma unroll
            for (int i = 0; i < 4; ++i) {
                int m = rowbase + mi * 16 + quad * 4 + i;
                if (m < N_OUT_) {
                    float v = acc[mi][nt][i] + bn;
                    v = (v > 0.0f) ? v : expm1f(v);
                    out[((size_t)b * N_OUT_ + m) * C_ + nt * 16 + l16] = v;
                }
            }
        }
    }
}

extern "C" void kernel_launch(void* const* d_in, const int* in_sizes, int n_in,
                              void* d_out, int out_size, void* d_ws, size_t ws_size,
                              hipStream_t stream) {
    const float* x      = (const float*)d_in[0];
    const float* tvals  = (const float*)d_in[1];
    const int*   trow   = (const int*)d_in[2];
    const int*   tcol   = (const int*)d_in[3];
    const int*   spiral = (const int*)d_in[4];
    const float* W      = (const float*)d_in[5];
    const float* bias   = (const float*)d_in[6];
    float* out = (float*)d_out;

    char* ws = (char*)d_ws;
    size_t off = 0;
    auto alloc = [&](size_t bytes) -> void* {
        void* p = ws + off;
        off += (bytes + 255) & ~(size_t)255;
        return p;
    };
    __bf16* pooled  = (__bf16*)alloc((size_t)B_ * N_OUT_ * C_ * 2);   // 51.2 MB
    __bf16* Wt      = (__bf16*)alloc(576 * 64 * 2);
    int*    cursor  = (int*)alloc(N_OUT_ * 4);          // counts -> cursor
    int*    offsets = (int*)alloc((N_OUT_ + 1) * 4);
    int*    ecol    = (int*)alloc(NNZ_ * 4);
    float*  eval    = (float*)alloc(NNZ_ * 4);

    hipMemsetAsync(cursor, 0, N_OUT_ * 4, stream);
    hist_kernel<<<(NNZ_ + 255) / 256, 256, 0, stream>>>(trow, cursor, NNZ_);
    scan_kernel<<<1, 1024, 0, stream>>>(cursor, offsets, N_OUT_);
    fill_kernel<<<(NNZ_ + 255) / 256, 256, 0, stream>>>(trow, tcol, tvals, cursor, ecol, eval, NNZ_);
    pool_kernel<<<N_OUT_, 256, 0, stream>>>(x, offsets, ecol, eval, pooled);
    convw_kernel<<<(576 * 64 + 255) / 256, 256, 0, stream>>>(W, Wt);
    gemm_kernel<<<dim3((N_OUT_ + 255) / 256, B_), 256, 0, stream>>>(pooled, spiral, Wt, bias, out);
}

// Round 3
// 326.178 us; speedup vs baseline: 1.2966x; 1.0978x over previous
//
#include <hip/hip_runtime.h>

#define B_     16
#define N_IN_  6250
#define N_OUT_ 25000
#define C_     64
#define S_     9
#define NNZ_   75000
#define PROW_  (B_ * C_)   // 1024 elements per pooled row (2 KB)

typedef __bf16 bf16x8 __attribute__((ext_vector_type(8)));
typedef float floatx4 __attribute__((ext_vector_type(4)));

// ---------------- CSR build ----------------

__global__ void hist_kernel(const int* __restrict__ rows, int* __restrict__ counts, int nnz) {
    int i = blockIdx.x * blockDim.x + threadIdx.x;
    if (i < nnz) atomicAdd(&counts[rows[i]], 1);
}

// scan1: per-block exclusive scan of counts -> offsets (block-local), block sums -> bsum
__global__ void scan1_kernel(const int* __restrict__ counts, int* __restrict__ offsets,
                             int* __restrict__ bsum, int n) {
    __shared__ int wsum[16];
    int t = threadIdx.x;
    int wid = t >> 6, lane = t & 63;
    int i = blockIdx.x * 1024 + t;
    int v = (i < n) ? counts[i] : 0;
    int s = v;
    #pragma unroll
    for (int d = 1; d < 64; d <<= 1) {
        int u = __shfl_up(s, d, 64);
        if (lane >= d) s += u;
    }
    if (lane == 63) wsum[wid] = s;
    __syncthreads();
    if (wid == 0 && lane < 16) {
        int ws = wsum[lane];
        #pragma unroll
        for (int d = 1; d < 16; d <<= 1) {
            int u = __shfl_up(ws, d, 64);
            if (lane >= d) ws += u;
        }
        wsum[lane] = ws;
    }
    __syncthreads();
    int wave_off = (wid == 0) ? 0 : wsum[wid - 1];
    int incl = s + wave_off;
    if (i < n) offsets[i] = incl - v;
    if (t == 1023) bsum[blockIdx.x] = incl;
}

// scan2: serial exclusive scan of 25 block sums; writes offsets[n] = total
__global__ void scan2_kernel(int* __restrict__ bsum, int* __restrict__ offsets, int nblk, int n) {
    if (threadIdx.x == 0) {
        int t = 0;
        for (int i = 0; i < nblk; ++i) { int v = bsum[i]; bsum[i] = t; t += v; }
        offsets[n] = t;
    }
}

// scan3: add block offsets, init cursor
__global__ void scan3_kernel(int* __restrict__ offsets, const int* __restrict__ bsum,
                             int* __restrict__ cursor, int n) {
    int i = blockIdx.x * 1024 + threadIdx.x;
    if (i < n) {
        int o = offsets[i] + bsum[blockIdx.x];
        offsets[i] = o;
        cursor[i] = o;
    }
}

__global__ void fill_kernel(const int* __restrict__ rows, const int* __restrict__ cols,
                            const float* __restrict__ vals, int* __restrict__ cursor,
                            int* __restrict__ ecol, float* __restrict__ eval, int nnz) {
    int i = blockIdx.x * blockDim.x + threadIdx.x;
    if (i < nnz) {
        int p = atomicAdd(&cursor[rows[i]], 1);
        ecol[p] = cols[i];
        eval[p] = vals[i];
    }
}

// ---------------- pooling (CSR gather), all batches per block ----------------
// grid: N_OUT blocks, block 256. Thread (bq, c): batches bq*4..bq*4+3, channel c.
// Writes pooled in batch-interleaved layout [N_OUT][B][C] bf16.
__global__ __launch_bounds__(256) void pool_kernel(
        const float* __restrict__ x, const int* __restrict__ offsets,
        const int* __restrict__ ecol, const float* __restrict__ eval,
        __bf16* __restrict__ pooled) {
    __shared__ int   scol[64];
    __shared__ float sval[64];
    int row = blockIdx.x;
    int t = threadIdx.x;
    int c = t & 63, bq = t >> 6;
    int beg = offsets[row], end = offsets[row + 1];
    int count = end - beg;

    float acc[4] = {0.f, 0.f, 0.f, 0.f};
    for (int base = 0; base < count; base += 64) {
        int nb = min(64, count - base);
        if (t < nb) {
            scol[t] = ecol[beg + base + t];
            sval[t] = eval[beg + base + t];
        }
        __syncthreads();
        for (int k = 0; k < nb; ++k) {
            int col = scol[k];
            float v = sval[k];
            const float* xp = x + ((size_t)col * C_ + c);
            #pragma unroll
            for (int j = 0; j < 4; ++j) {
                acc[j] += xp[(size_t)(bq * 4 + j) * N_IN_ * C_] * v;
            }
        }
        __syncthreads();
    }
    #pragma unroll
    for (int j = 0; j < 4; ++j) {
        pooled[(size_t)row * PROW_ + (bq * 4 + j) * C_ + c] = (__bf16)acc[j];
    }
}

// ---------------- W -> Wt (bf16, transposed [64][576]) ----------------
__global__ void convw_kernel(const float* __restrict__ W, __bf16* __restrict__ Wt) {
    int i = blockIdx.x * blockDim.x + threadIdx.x;   // over 576*64
    if (i < 576 * 64) {
        int k = i >> 6, n = i & 63;
        Wt[n * 576 + k] = (__bf16)W[i];
    }
}

// ---------------- spiral gather + GEMM + bias + ELU ----------------
// NO LDS, NO BARRIERS, register-double-buffered.
// grid: (ceil(N_OUT/64), 4), block 256 (4 waves).
// Wave = 16 m-rows x 64 cols x 4 batches (bg*4..bg*4+3).
// pooled is [N_OUT][16][64] bf16: one src row = 2 KB covering all batches.
__global__ __launch_bounds__(256, 2) void gemm_kernel(
        const __bf16* __restrict__ pooled, const int* __restrict__ spiral,
        const __bf16* __restrict__ Wt, const float* __restrict__ bias,
        float* __restrict__ out) {
    int b0 = blockIdx.y * 4;
    int t = threadIdx.x;
    int wave = t >> 6, lane = t & 63;
    int quad = lane >> 4, l16 = lane & 15;
    int mbase = blockIdx.x * 64 + wave * 16;
    int m = mbase + l16;                 // this lane's A-row
    int mc = (m < N_OUT_) ? m : 0;

    // preload all 9 spiral indices (independent scalar loads)
    int src[S_];
    #pragma unroll
    for (int s = 0; s < S_; ++s) src[s] = spiral[mc * S_ + s];

    floatx4 acc[4][4] = {};   // [batch][nt]
    bf16x8 aA[8], aB[8], bA[8], bB[8];   // ping-pong frag buffers [j*2+kc]

    auto aload = [&](int s, bf16x8* a) {
        const __bf16* base = pooled + (size_t)src[s] * PROW_ + quad * 8;
        #pragma unroll
        for (int j = 0; j < 4; ++j)
            #pragma unroll
            for (int kc = 0; kc < 2; ++kc)
                a[j * 2 + kc] = *reinterpret_cast<const bf16x8*>(
                    base + (b0 + j) * C_ + kc * 32);
    };
    auto bload = [&](int s, bf16x8* bb) {
        const __bf16* base = Wt + l16 * 576 + s * 64 + quad * 8;
        #pragma unroll
        for (int nt = 0; nt < 4; ++nt)
            #pragma unroll
            for (int kc = 0; kc < 2; ++kc)
                bb[nt * 2 + kc] = *reinterpret_cast<const bf16x8*>(
                    base + nt * 16 * 576 + kc * 32);
    };
    auto mmac = [&](bf16x8* a, bf16x8* bb) {
        #pragma unroll
        for (int kc = 0; kc < 2; ++kc)
            #pragma unroll
            for (int j = 0; j < 4; ++j)
                #pragma unroll
                for (int nt = 0; nt < 4; ++nt)
                    acc[j][nt] = __builtin_amdgcn_mfma_f32_16x16x32_bf16(
                        a[j * 2 + kc], bb[nt * 2 + kc], acc[j][nt], 0, 0, 0);
    };

    aload(0, aA); bload(0, bA);
    #pragma unroll
    for (int sp = 0; sp < 4; ++sp) {
        int s = sp * 2;
        aload(s + 1, aB); bload(s + 1, bB);
        mmac(aA, bA);
        aload(s + 2, aA); bload(s + 2, bA);
        mmac(aB, bB);
    }
    mmac(aA, bA);   // s = 8

    // epilogue: tile D[m = quad*4 + reg][n = l16]
    #pragma unroll
    for (int nt = 0; nt < 4; ++nt) {
        float bn = bias[nt * 16 + l16];
        #pragma unroll
        for (int j = 0; j < 4; ++j) {
            #pragma unroll
            for (int i = 0; i < 4; ++i) {
                int mm = mbase + quad * 4 + i;
                if (mm < N_OUT_) {
                    float v = acc[j][nt][i] + bn;
                    v = (v > 0.0f) ? v : expm1f(v);
                    out[((size_t)(b0 + j) * N_OUT_ + mm) * C_ + nt * 16 + l16] = v;
                }
            }
        }
    }
}

extern "C" void kernel_launch(void* const* d_in, const int* in_sizes, int n_in,
                              void* d_out, int out_size, void* d_ws, size_t ws_size,
                              hipStream_t stream) {
    const float* x      = (const float*)d_in[0];
    const float* tvals  = (const float*)d_in[1];
    const int*   trow   = (const int*)d_in[2];
    const int*   tcol   = (const int*)d_in[3];
    const int*   spiral = (const int*)d_in[4];
    const float* W      = (const float*)d_in[5];
    const float* bias   = (const float*)d_in[6];
    float* out = (float*)d_out;

    char* ws = (char*)d_ws;
    size_t off = 0;
    auto alloc = [&](size_t bytes) -> void* {
        void* p = ws + off;
        off += (bytes + 255) & ~(size_t)255;
        return p;
    };
    __bf16* pooled  = (__bf16*)alloc((size_t)N_OUT_ * PROW_ * 2);   // 51.2 MB
    __bf16* Wt      = (__bf16*)alloc(576 * 64 * 2);
    int*    cursor  = (int*)alloc(N_OUT_ * 4);
    int*    offsets = (int*)alloc((N_OUT_ + 1) * 4);
    int*    ecol    = (int*)alloc(NNZ_ * 4);
    float*  eval    = (float*)alloc(NNZ_ * 4);
    int*    counts  = (int*)alloc(N_OUT_ * 4);
    int*    bsum    = (int*)alloc(32 * 4);

    const int NBLK = (N_OUT_ + 1023) / 1024;   // 25
    hipMemsetAsync(counts, 0, N_OUT_ * 4, stream);
    hist_kernel<<<(NNZ_ + 255) / 256, 256, 0, stream>>>(trow, counts, NNZ_);
    scan1_kernel<<<NBLK, 1024, 0, stream>>>(counts, offsets, bsum, N_OUT_);
    scan2_kernel<<<1, 64, 0, stream>>>(bsum, offsets, NBLK, N_OUT_);
    scan3_kernel<<<NBLK, 1024, 0, stream>>>(offsets, bsum, cursor, N_OUT_);
    fill_kernel<<<(NNZ_ + 255) / 256, 256, 0, stream>>>(trow, tcol, tvals, cursor, ecol, eval, NNZ_);
    pool_kernel<<<N_OUT_, 256, 0, stream>>>(x, offsets, ecol, eval, pooled);
    convw_kernel<<<(576 * 64 + 255) / 256, 256, 0, stream>>>(W, Wt);
    gemm_kernel<<<dim3((N_OUT_ + 63) / 64, 4), 256, 0, stream>>>(pooled, spiral, Wt, bias, out);
}